// Round 4
// baseline (25.460 us; speedup 1.0000x reference)
//
#include <hip/hip_runtime.h>

// HammingLoss: loss = mean_i popcount(code[output[i]] ^ code[target[i]])
// code[c] = 64-bit packing of coding_table[c, :] (values are exactly 0.0/1.0).
//
// 2 dispatches:
//   1) pack_init: table -> packed u64 codes (one 64-lane wave per class,
//      __ballot); zeroes acc + counter (ws is poisoned 0xAA once and never
//      re-poisoned, so every call must self-init).
//   2) hamming_finalize: all 4 grid-stride iterations' index loads issued
//      up-front (8x int4 in flight, one latency exposure) BEFORE LDS staging,
//      then 32 LDS gathers + popcount, wave/block reduce, one u64 atomic per
//      block, last-block-done finalize (release fence -> counter; last block
//      acquire-fences and atomically re-reads acc -- safe across non-coherent
//      per-XCD L2s).
//
// Working set (16.8 MB indices + table) is L2/L3-resident across graph
// replays, so the lever is outstanding-load count, not bytes. Do NOT use
// nontemporal loads.
//
// ws layout:
//   [0,    8000) : unsigned long long codes[1000]
//   [8192, 8200) : unsigned long long acc
//   [8200, 8204) : unsigned int      counter

#define N_CLASSES 1000
#define CODE_LEN  64
#define MAIN_BLOCKS 512
#define KBATCH 4

__global__ void pack_init_kernel(const float* __restrict__ table,
                                 unsigned long long* __restrict__ codes,
                                 unsigned long long* __restrict__ acc,
                                 unsigned int* __restrict__ counter) {
    int gtid = blockIdx.x * blockDim.x + threadIdx.x;
    if (gtid == 0) { *acc = 0ULL; *counter = 0u; }

    int wave = gtid >> 6;          // one 64-lane wave per class
    int lane = threadIdx.x & 63;
    if (wave < N_CLASSES) {
        float v = table[wave * CODE_LEN + lane];          // coalesced 256B/wave
        unsigned long long mask = __ballot(v > 0.5f);     // 64-bit ballot
        if (lane == 0) codes[wave] = mask;
    }
}

__global__ void __launch_bounds__(256)
hamming_finalize_kernel(const int* __restrict__ out_idx,
                        const int* __restrict__ tgt_idx,
                        const unsigned long long* __restrict__ codes,
                        unsigned long long* __restrict__ acc,
                        unsigned int* __restrict__ counter,
                        float* __restrict__ out,
                        int nvec, int n) {
    __shared__ unsigned long long s_codes[N_CLASSES];

    const int4* o4 = (const int4*)out_idx;
    const int4* t4 = (const int4*)tgt_idx;

    int tid0   = blockIdx.x * blockDim.x + threadIdx.x;
    int stride = gridDim.x * blockDim.x;

    // Issue ALL KBATCH iterations' global loads up-front: one latency
    // exposure, hidden under LDS staging + barrier. Static indexing only.
    int4 ob[KBATCH], tb[KBATCH];
    bool vb[KBATCH];
    #pragma unroll
    for (int k = 0; k < KBATCH; ++k) {
        int i = tid0 + k * stride;
        vb[k] = (i < nvec);
        if (vb[k]) { ob[k] = o4[i]; tb[k] = t4[i]; }
    }

    // stage packed table (8 KB) as 16B vectors
    {
        const ulonglong2* src = (const ulonglong2*)codes;
        ulonglong2*       dst = (ulonglong2*)s_codes;
        for (int i = threadIdx.x; i < N_CLASSES / 2; i += blockDim.x)
            dst[i] = src[i];
    }
    __syncthreads();

    int sum = 0;
    #pragma unroll
    for (int k = 0; k < KBATCH; ++k) {
        if (vb[k]) {
            sum += __popcll(s_codes[ob[k].x] ^ s_codes[tb[k].x]);
            sum += __popcll(s_codes[ob[k].y] ^ s_codes[tb[k].y]);
            sum += __popcll(s_codes[ob[k].z] ^ s_codes[tb[k].z]);
            sum += __popcll(s_codes[ob[k].w] ^ s_codes[tb[k].w]);
        }
    }
    // any iterations beyond the batched KBATCH (not taken at B=2M, 512 blocks)
    for (int i = tid0 + KBATCH * stride; i < nvec; i += stride) {
        int4 o = o4[i];
        int4 t = t4[i];
        sum += __popcll(s_codes[o.x] ^ s_codes[t.x]);
        sum += __popcll(s_codes[o.y] ^ s_codes[t.y]);
        sum += __popcll(s_codes[o.z] ^ s_codes[t.z]);
        sum += __popcll(s_codes[o.w] ^ s_codes[t.w]);
    }
    // scalar tail (n % 4)
    for (int i = nvec * 4 + tid0; i < n; i += stride) {
        sum += __popcll(s_codes[out_idx[i]] ^ s_codes[tgt_idx[i]]);
    }

    // 64-lane wave reduce
    #pragma unroll
    for (int off = 32; off >= 1; off >>= 1)
        sum += __shfl_down(sum, off);

    __shared__ int s_part[4];      // 256 threads = 4 waves
    int wid  = threadIdx.x >> 6;
    int lane = threadIdx.x & 63;
    if (lane == 0) s_part[wid] = sum;
    __syncthreads();

    if (threadIdx.x == 0) {
        unsigned long long tot =
            (unsigned long long)(s_part[0] + s_part[1] + s_part[2] + s_part[3]);
        atomicAdd(acc, tot);
        __threadfence();                           // release: acc-add before ctr-add
        unsigned int done = atomicAdd(counter, 1u);
        if (done == gridDim.x - 1) {               // last block to finish
            __threadfence();                       // acquire
            unsigned long long total = atomicAdd(acc, 0ULL);  // coherent re-read
            out[0] = (float)((double)total / (double)n);
        }
    }
}

extern "C" void kernel_launch(void* const* d_in, const int* in_sizes, int n_in,
                              void* d_out, int out_size, void* d_ws, size_t ws_size,
                              hipStream_t stream) {
    const int*   out_idx = (const int*)d_in[0];
    const int*   tgt_idx = (const int*)d_in[1];
    const float* table   = (const float*)d_in[2];
    float*       out     = (float*)d_out;

    int n = in_sizes[0];

    unsigned long long* codes   = (unsigned long long*)d_ws;
    unsigned long long* acc     = (unsigned long long*)((char*)d_ws + 8192);
    unsigned int*       counter = (unsigned int*)((char*)d_ws + 8200);

    // 1) pack table -> u64 codes; zero acc/counter
    {
        int threads = 256;                               // 4 waves/block
        int blocks = (N_CLASSES * 64 + threads - 1) / threads;  // 250
        pack_init_kernel<<<blocks, threads, 0, stream>>>(table, codes, acc, counter);
    }

    // 2) main reduce + last-block finalize
    {
        int nvec = n / 4;
        int threads = 256;
        int blocks = MAIN_BLOCKS;                        // 4 int4 iters/thread at B=2M
        int max_blocks = (nvec + threads - 1) / threads;
        if (blocks > max_blocks) blocks = max_blocks;
        if (blocks < 1) blocks = 1;
        hamming_finalize_kernel<<<blocks, threads, 0, stream>>>(
            out_idx, tgt_idx, codes, acc, counter, out, nvec, n);
    }
}

// Round 5
// 16.009 us; speedup vs baseline: 1.5903x; 1.5903x over previous
//
#include <hip/hip_runtime.h>

// HammingLoss: loss = mean_i popcount(code[output[i]] ^ code[target[i]])
// code[c] = 64-bit packing of coding_table[c, :] (values are exactly 0.0/1.0).
//
// ZERO-ATOMIC design (R4 post-mortem: ~1024 single-address device atomics were
// ~12 us of the window -- ~12 ns each serialized at the cross-XCD coherence
// point; R2->R3's -12.5 us tracked the halving of atomic count, not the load
// batching, which was null R3->R4).
//
// 3 dispatches:
//   1) pack_init: table -> packed u64 codes (one 64-lane wave per class,
//      __ballot). Nothing to zero: partials/out are fully rewritten each call.
//   2) hamming: int4-vectorized index loads (4 iters batched up-front), LDS
//      code table, popcount-XOR, wave+block reduce, PLAIN STORE of the block
//      partial to its own u64 slot. No atomics, no fences: kernel completion
//      is a system-scope release, so the next dispatch sees all partials
//      (safe across non-coherent per-XCD L2s).
//   3) finalize: one 64-lane wave sums the partials, writes sum / n.
//
// Working set (16.8 MB indices + table) is L2/L3-resident; device-work floor
// ~3 us. Do NOT use nontemporal loads.
//
// ws layout:
//   [0,    8000)        : unsigned long long codes[1000]
//   [8192, 8192+4096)   : unsigned long long partials[MAIN_BLOCKS]

#define N_CLASSES 1000
#define CODE_LEN  64
#define MAIN_BLOCKS 512
#define KBATCH 4

__global__ void pack_init_kernel(const float* __restrict__ table,
                                 unsigned long long* __restrict__ codes) {
    int gtid = blockIdx.x * blockDim.x + threadIdx.x;
    int wave = gtid >> 6;          // one 64-lane wave per class
    int lane = threadIdx.x & 63;
    if (wave < N_CLASSES) {
        float v = table[wave * CODE_LEN + lane];          // coalesced 256B/wave
        unsigned long long mask = __ballot(v > 0.5f);     // 64-bit ballot
        if (lane == 0) codes[wave] = mask;
    }
}

__global__ void __launch_bounds__(256)
hamming_kernel(const int* __restrict__ out_idx,
               const int* __restrict__ tgt_idx,
               const unsigned long long* __restrict__ codes,
               unsigned long long* __restrict__ partials,
               int nvec, int n) {
    __shared__ unsigned long long s_codes[N_CLASSES];

    const int4* o4 = (const int4*)out_idx;
    const int4* t4 = (const int4*)tgt_idx;

    int tid0   = blockIdx.x * blockDim.x + threadIdx.x;
    int stride = gridDim.x * blockDim.x;

    // Issue all KBATCH iterations' global loads up-front: one latency
    // exposure, hidden under LDS staging + barrier. Static indexing only.
    int4 ob[KBATCH], tb[KBATCH];
    bool vb[KBATCH];
    #pragma unroll
    for (int k = 0; k < KBATCH; ++k) {
        int i = tid0 + k * stride;
        vb[k] = (i < nvec);
        if (vb[k]) { ob[k] = o4[i]; tb[k] = t4[i]; }
    }

    // stage packed table (8 KB) as 16B vectors
    {
        const ulonglong2* src = (const ulonglong2*)codes;
        ulonglong2*       dst = (ulonglong2*)s_codes;
        for (int i = threadIdx.x; i < N_CLASSES / 2; i += blockDim.x)
            dst[i] = src[i];
    }
    __syncthreads();

    int sum = 0;
    #pragma unroll
    for (int k = 0; k < KBATCH; ++k) {
        if (vb[k]) {
            sum += __popcll(s_codes[ob[k].x] ^ s_codes[tb[k].x]);
            sum += __popcll(s_codes[ob[k].y] ^ s_codes[tb[k].y]);
            sum += __popcll(s_codes[ob[k].z] ^ s_codes[tb[k].z]);
            sum += __popcll(s_codes[ob[k].w] ^ s_codes[tb[k].w]);
        }
    }
    // iterations beyond KBATCH (not taken at B=2M with 512 blocks)
    for (int i = tid0 + KBATCH * stride; i < nvec; i += stride) {
        int4 o = o4[i];
        int4 t = t4[i];
        sum += __popcll(s_codes[o.x] ^ s_codes[t.x]);
        sum += __popcll(s_codes[o.y] ^ s_codes[t.y]);
        sum += __popcll(s_codes[o.z] ^ s_codes[t.z]);
        sum += __popcll(s_codes[o.w] ^ s_codes[t.w]);
    }
    // scalar tail (n % 4)
    for (int i = nvec * 4 + tid0; i < n; i += stride) {
        sum += __popcll(s_codes[out_idx[i]] ^ s_codes[tgt_idx[i]]);
    }

    // 64-lane wave reduce
    #pragma unroll
    for (int off = 32; off >= 1; off >>= 1)
        sum += __shfl_down(sum, off);

    __shared__ int s_part[4];      // 256 threads = 4 waves
    int wid  = threadIdx.x >> 6;
    int lane = threadIdx.x & 63;
    if (lane == 0) s_part[wid] = sum;
    __syncthreads();

    if (threadIdx.x == 0) {
        partials[blockIdx.x] =
            (unsigned long long)(s_part[0] + s_part[1] + s_part[2] + s_part[3]);
    }
}

__global__ void finalize_kernel(const unsigned long long* __restrict__ partials,
                                float* __restrict__ out, int nblocks, int n) {
    // single 64-lane wave; each lane sums a strided slice, then shfl-reduce
    unsigned long long s = 0;
    for (int i = threadIdx.x; i < nblocks; i += 64)
        s += partials[i];
    #pragma unroll
    for (int off = 32; off >= 1; off >>= 1)
        s += __shfl_down(s, off);
    if (threadIdx.x == 0)
        out[0] = (float)((double)s / (double)n);
}

extern "C" void kernel_launch(void* const* d_in, const int* in_sizes, int n_in,
                              void* d_out, int out_size, void* d_ws, size_t ws_size,
                              hipStream_t stream) {
    const int*   out_idx = (const int*)d_in[0];
    const int*   tgt_idx = (const int*)d_in[1];
    const float* table   = (const float*)d_in[2];
    float*       out     = (float*)d_out;

    int n = in_sizes[0];

    unsigned long long* codes    = (unsigned long long*)d_ws;
    unsigned long long* partials = (unsigned long long*)((char*)d_ws + 8192);

    // 1) pack table -> u64 codes
    {
        int threads = 256;                               // 4 waves/block
        int blocks = (N_CLASSES * 64 + threads - 1) / threads;  // 250
        pack_init_kernel<<<blocks, threads, 0, stream>>>(table, codes);
    }

    // 2) main reduce -> per-block partials (plain stores, no atomics)
    int nblocks;
    {
        int nvec = n / 4;
        int threads = 256;
        nblocks = MAIN_BLOCKS;                           // 4 int4 iters/thread at B=2M
        int max_blocks = (nvec + threads - 1) / threads;
        if (nblocks > max_blocks) nblocks = max_blocks;
        if (nblocks < 1) nblocks = 1;
        hamming_kernel<<<nblocks, threads, 0, stream>>>(
            out_idx, tgt_idx, codes, partials, nvec, n);
    }

    // 3) finalize: sum partials, divide
    finalize_kernel<<<1, 64, 0, stream>>>(partials, out, nblocks, n);
}

// Round 6
// 15.308 us; speedup vs baseline: 1.6631x; 1.0458x over previous
//
#include <hip/hip_runtime.h>

// HammingLoss: loss = mean_i popcount(code[output[i]] ^ code[target[i]])
// code[c] = 64-bit packing of coding_table[c, :] (values are exactly 0.0/1.0).
//
// ZERO-ATOMIC design (R4->R5 confirmed: ~1024 device-scope same-line atomics
// cost ~10 us; plain per-block partial stores + separate finalize dispatch is
// ~9.5 us faster despite the extra node).
//
// 3 dispatches:
//   1) pack_init: table -> packed u64 codes (one 64-lane wave per class,
//      __ballot). Nothing to zero: partials/out are fully rewritten each call.
//   2) hamming: 1024 blocks x KBATCH=2 (R5: atomics gone, so block count no
//      longer carries serialization cost -- maximize TLP). Index loads batched
//      up-front, LDS code table, popcount-XOR, wave+block reduce, plain store
//      of block partial (kernel completion = system-scope release; safe
//      across non-coherent per-XCD L2s).
//   3) finalize: 512 threads, one coalesced partial load each (one memory
//      round-trip, was 8 serial/lane), wave shfl + LDS tree, out = sum / n.
//
// Working set (16.8 MB indices + table) is L2/L3-resident; do NOT use
// nontemporal loads.
//
// ws layout:
//   [0,    8000)   : unsigned long long codes[1000]
//   [8192, 16384)  : unsigned long long partials[MAIN_BLOCKS]

#define N_CLASSES 1000
#define CODE_LEN  64
#define MAIN_BLOCKS 1024
#define KBATCH 2

__global__ void pack_init_kernel(const float* __restrict__ table,
                                 unsigned long long* __restrict__ codes) {
    int gtid = blockIdx.x * blockDim.x + threadIdx.x;
    int wave = gtid >> 6;          // one 64-lane wave per class
    int lane = threadIdx.x & 63;
    if (wave < N_CLASSES) {
        float v = table[wave * CODE_LEN + lane];          // coalesced 256B/wave
        unsigned long long mask = __ballot(v > 0.5f);     // 64-bit ballot
        if (lane == 0) codes[wave] = mask;
    }
}

__global__ void __launch_bounds__(256)
hamming_kernel(const int* __restrict__ out_idx,
               const int* __restrict__ tgt_idx,
               const unsigned long long* __restrict__ codes,
               unsigned long long* __restrict__ partials,
               int nvec, int n) {
    __shared__ unsigned long long s_codes[N_CLASSES];

    const int4* o4 = (const int4*)out_idx;
    const int4* t4 = (const int4*)tgt_idx;

    int tid0   = blockIdx.x * blockDim.x + threadIdx.x;
    int stride = gridDim.x * blockDim.x;

    // Issue all KBATCH iterations' global loads up-front: one latency
    // exposure, hidden under LDS staging + barrier. Static indexing only.
    int4 ob[KBATCH], tb[KBATCH];
    bool vb[KBATCH];
    #pragma unroll
    for (int k = 0; k < KBATCH; ++k) {
        int i = tid0 + k * stride;
        vb[k] = (i < nvec);
        if (vb[k]) { ob[k] = o4[i]; tb[k] = t4[i]; }
    }

    // stage packed table (8 KB) as 16B vectors
    {
        const ulonglong2* src = (const ulonglong2*)codes;
        ulonglong2*       dst = (ulonglong2*)s_codes;
        for (int i = threadIdx.x; i < N_CLASSES / 2; i += blockDim.x)
            dst[i] = src[i];
    }
    __syncthreads();

    int sum = 0;
    #pragma unroll
    for (int k = 0; k < KBATCH; ++k) {
        if (vb[k]) {
            sum += __popcll(s_codes[ob[k].x] ^ s_codes[tb[k].x]);
            sum += __popcll(s_codes[ob[k].y] ^ s_codes[tb[k].y]);
            sum += __popcll(s_codes[ob[k].z] ^ s_codes[tb[k].z]);
            sum += __popcll(s_codes[ob[k].w] ^ s_codes[tb[k].w]);
        }
    }
    // iterations beyond KBATCH (not taken at B=2M with 1024 blocks)
    for (int i = tid0 + KBATCH * stride; i < nvec; i += stride) {
        int4 o = o4[i];
        int4 t = t4[i];
        sum += __popcll(s_codes[o.x] ^ s_codes[t.x]);
        sum += __popcll(s_codes[o.y] ^ s_codes[t.y]);
        sum += __popcll(s_codes[o.z] ^ s_codes[t.z]);
        sum += __popcll(s_codes[o.w] ^ s_codes[t.w]);
    }
    // scalar tail (n % 4)
    for (int i = nvec * 4 + tid0; i < n; i += stride) {
        sum += __popcll(s_codes[out_idx[i]] ^ s_codes[tgt_idx[i]]);
    }

    // 64-lane wave reduce
    #pragma unroll
    for (int off = 32; off >= 1; off >>= 1)
        sum += __shfl_down(sum, off);

    __shared__ int s_part[4];      // 256 threads = 4 waves
    int wid  = threadIdx.x >> 6;
    int lane = threadIdx.x & 63;
    if (lane == 0) s_part[wid] = sum;
    __syncthreads();

    if (threadIdx.x == 0) {
        partials[blockIdx.x] =
            (unsigned long long)(s_part[0] + s_part[1] + s_part[2] + s_part[3]);
    }
}

__global__ void __launch_bounds__(512)
finalize_kernel(const unsigned long long* __restrict__ partials,
                float* __restrict__ out, int nblocks, int n) {
    // 512 threads: one coalesced partial load each (single memory round-trip),
    // then 64-lane shfl reduce + 8-wave LDS tree.
    unsigned long long s = 0;
    for (int i = threadIdx.x; i < nblocks; i += 512)
        s += partials[i];
    #pragma unroll
    for (int off = 32; off >= 1; off >>= 1)
        s += __shfl_down(s, off);

    __shared__ unsigned long long s_f[8];
    int wid  = threadIdx.x >> 6;
    int lane = threadIdx.x & 63;
    if (lane == 0) s_f[wid] = s;
    __syncthreads();
    if (threadIdx.x == 0) {
        unsigned long long tot = 0;
        #pragma unroll
        for (int w = 0; w < 8; ++w) tot += s_f[w];
        out[0] = (float)((double)tot / (double)n);
    }
}

extern "C" void kernel_launch(void* const* d_in, const int* in_sizes, int n_in,
                              void* d_out, int out_size, void* d_ws, size_t ws_size,
                              hipStream_t stream) {
    const int*   out_idx = (const int*)d_in[0];
    const int*   tgt_idx = (const int*)d_in[1];
    const float* table   = (const float*)d_in[2];
    float*       out     = (float*)d_out;

    int n = in_sizes[0];

    unsigned long long* codes    = (unsigned long long*)d_ws;
    unsigned long long* partials = (unsigned long long*)((char*)d_ws + 8192);

    // 1) pack table -> u64 codes
    {
        int threads = 256;                               // 4 waves/block
        int blocks = (N_CLASSES * 64 + threads - 1) / threads;  // 250
        pack_init_kernel<<<blocks, threads, 0, stream>>>(table, codes);
    }

    // 2) main reduce -> per-block partials (plain stores, no atomics)
    int nblocks;
    {
        int nvec = n / 4;
        int threads = 256;
        nblocks = MAIN_BLOCKS;                           // 2 int4 iters/thread at B=2M
        int max_blocks = (nvec + threads - 1) / threads;
        if (nblocks > max_blocks) nblocks = max_blocks;
        if (nblocks < 1) nblocks = 1;
        hamming_kernel<<<nblocks, threads, 0, stream>>>(
            out_idx, tgt_idx, codes, partials, nvec, n);
    }

    // 3) finalize: sum partials, divide
    finalize_kernel<<<1, 512, 0, stream>>>(partials, out, nblocks, n);
}